// Round 10
// baseline (200.068 us; speedup 1.0000x reference)
//
#include <hip/hip_runtime.h>

// y = softmax((xWq+bq)(xWk+bk)^T / sqrt(64)) (xWv+bv), per head, NO causal mask.
// B=2, S=2048, D=1024, H=16, hd=64. Input dtype sniffed on-device (fp32 vs bf16).
// R1: csc folded into Q epilogue; v_cvt_pk_bf16_f32 packs. (kept)
// R2: dbuf+prefetch attn — REGRESSED (occupancy 19->11%). Reverted.
// R3: 64-q blocks (grid 1024, 4 blk/CU), XCD swizzle (FETCH 70->12MB). (kept)
// R4: [64][64] LDS + XOR swizzle + gl_lds staging (conflicts 11.5M->2.1M). (kept)
// R5: attn dbuf+prefetch+setprio — REGRESSED (82.7us, +12MB HBM writes). Reverted.
// R6: GEMM BK 32->64 halves barrier-drain events; swizzled [128][64] LDS +
//     pre-swizzled gl_lds source (same pattern as R4 attn staging).
// R9: FIX R6 bug — fragment k-slice loop was ks<4/ks*16 (out-of-bounds, k
//     overlap -> NaN). Correct: ks<2, colu = ks*32 + lk*8 (attn pattern).

#define D_MODEL 1024
#define NHEAD   16
#define HDIM    64
#define SEQ     2048
#define CSC     0.18033688011112042f   // log2(e)/sqrt(64)

typedef __attribute__((ext_vector_type(8))) short short8;
typedef __attribute__((ext_vector_type(4))) float f32x4;

__device__ __forceinline__ float bf2f(unsigned short u) {
  return __uint_as_float(((unsigned int)u) << 16);
}
__device__ __forceinline__ unsigned short f2bf(float f) {
  unsigned int u = __float_as_uint(f);
  u += 0x7fff + ((u >> 16) & 1);   // RNE
  return (unsigned short)(u >> 16);
}
__device__ __forceinline__ unsigned int cvtpk_bf16(float lo, float hi) {
  unsigned int r;
  asm("v_cvt_pk_bf16_f32 %0, %1, %2" : "=v"(r) : "v"(lo), "v"(hi));
  return r;
}

__device__ __forceinline__ int sniff_bf16(const unsigned short* x) {
  int cnt = 0;
#pragma unroll
  for (int i = 0; i < 64; ++i) {
    const unsigned e = (x[2 * i] >> 7) & 0xFF;
    cnt += (e >= 105 && e <= 140) ? 1 : 0;
  }
  return cnt >= 48;
}

__device__ __forceinline__ void gl_lds16(const unsigned short* g, unsigned short* l) {
  __builtin_amdgcn_global_load_lds(
      (const __attribute__((address_space(1))) unsigned int*)g,
      (__attribute__((address_space(3))) unsigned int*)l, 16, 0, 0);
}

// XOR swizzle for [N][64]-ushort LDS tiles (128B rows): 16B chunk ^= row&7.
__device__ __forceinline__ int swz(int row, int colu) {
  return row * 64 + (colu ^ ((row & 7) << 3));
}

// ============ pre-kernel A: X -> bf16 copy/convert ==========================
__global__ __launch_bounds__(256) void cvt_x(const unsigned short* __restrict__ X,
                                             unsigned short* __restrict__ Xbf) {
  const int isbf = sniff_bf16(X);
  const size_t i0 = ((size_t)blockIdx.x * 256 + threadIdx.x) * 8;
  if (isbf) {
    *(uint4*)(Xbf + i0) = *(const uint4*)(X + i0);
  } else {
    const float* Xf = (const float*)X;
    const float4 f0 = *(const float4*)(Xf + i0);
    const float4 f1 = *(const float4*)(Xf + i0 + 4);
    unsigned int t[4] = {cvtpk_bf16(f0.x, f0.y), cvtpk_bf16(f0.z, f0.w),
                         cvtpk_bf16(f1.x, f1.y), cvtpk_bf16(f1.z, f1.w)};
    *(uint4*)(Xbf + i0) = *(const uint4*)t;
  }
}

// ====== pre-kernel B: W -> Wt bf16 [n][k] (transpose), + bias -> bf16 =======
__global__ __launch_bounds__(256) void cvt_w(
    const unsigned short* __restrict__ w0, const unsigned short* __restrict__ w1,
    const unsigned short* __restrict__ w2,
    const unsigned short* __restrict__ b0, const unsigned short* __restrict__ b1,
    const unsigned short* __restrict__ b2,
    unsigned short* __restrict__ Wt, unsigned short* __restrict__ bb) {
  __shared__ unsigned short tile[32][33];
  const int z = blockIdx.z;
  const unsigned short* W    = (z == 0) ? w0 : ((z == 1) ? w1 : w2);
  const unsigned short* bias = (z == 0) ? b0 : ((z == 1) ? b1 : b2);
  unsigned short* Wtz = Wt + ((size_t)z << 20);
  const int isbf = sniff_bf16(W);
  const int bx = blockIdx.x * 32;
  const int by = blockIdx.y * 32;
  const int tx = threadIdx.x & 31;
  const int ty = threadIdx.x >> 5;
#pragma unroll
  for (int r = ty; r < 32; r += 8) {
    unsigned short v;
    if (isbf) v = W[(size_t)(by + r) * D_MODEL + bx + tx];
    else      v = f2bf(((const float*)W)[(size_t)(by + r) * D_MODEL + bx + tx]);
    tile[r][tx] = v;
  }
  __syncthreads();
#pragma unroll
  for (int r = ty; r < 32; r += 8)
    Wtz[(size_t)(bx + r) * D_MODEL + by + tx] = tile[tx][r];
  if (blockIdx.x == 0 && blockIdx.y == 0) {
    const int i0 = threadIdx.x * 4;
#pragma unroll
    for (int j = 0; j < 4; ++j)
      bb[z * D_MODEL + i0 + j] =
          isbf ? bias[i0 + j] : f2bf(((const float*)bias)[i0 + j]);
  }
}

// ===== shared epilogue helper =====
__device__ __forceinline__ void store_cd(int z, unsigned short* Out, int row0,
                                         int col, const f32x4 acc, float bb,
                                         float sc) {
  if (z == 2) {
    const int b = row0 >> 11, s = row0 & 2047;
    const int bh = b * NHEAD + (col >> 6);
    uint2 pk;
    pk.x = cvtpk_bf16(acc[0] + bb, acc[1] + bb);
    pk.y = cvtpk_bf16(acc[2] + bb, acc[3] + bb);
    *(uint2*)(Out + ((size_t)bh * HDIM + (col & 63)) * SEQ + s) = pk;
  } else {
#pragma unroll
    for (int r = 0; r < 4; ++r)
      Out[(size_t)(row0 + r) * D_MODEL + col] = f2bf((acc[r] + bb) * sc);
  }
}

// ============ kernel 1 (fast): BK=64 GEMM, swizzled LDS, global_load_lds ====
__global__ __launch_bounds__(256) void qkv_gemm_fast(
    const unsigned short* __restrict__ Xbf, const unsigned short* __restrict__ Wt,
    const unsigned short* __restrict__ bb,
    unsigned short* __restrict__ Oq, unsigned short* __restrict__ Ok,
    unsigned short* __restrict__ Ov) {
  const int z = blockIdx.z;
  const unsigned short* Wz = Wt + ((size_t)z << 20);
  unsigned short* Out = (z == 0) ? Oq : ((z == 1) ? Ok : Ov);
  const float sc = (z == 0) ? CSC : 1.0f;

  __shared__ alignas(16) unsigned short As[128 * 64];
  __shared__ alignas(16) unsigned short Bs[128 * 64];

  const int tid  = threadIdx.x;
  const int wave = tid >> 6, lane = tid & 63;
  const int wm = wave >> 1, wn = wave & 1;
  const int lrow = lane & 15, lk = lane >> 4;
  const int m0 = blockIdx.y * 128;
  const int n0 = blockIdx.x * 128;

  const unsigned short* Xa[4];
  const unsigned short* Wb[4];
#pragma unroll
  for (int i = 0; i < 4; ++i) {
    const int c = tid + i * 256, row = c >> 3;
    const int g = ((c & 7) ^ (row & 7)) * 8;   // pre-swizzled global chunk
    Xa[i] = Xbf + (size_t)(m0 + row) * D_MODEL + g;
    Wb[i] = Wz  + (size_t)(n0 + row) * D_MODEL + g;
  }

  f32x4 acc[4][4] = {};

  for (int kk = 0; kk < D_MODEL; kk += 64) {
#pragma unroll
    for (int i = 0; i < 4; ++i) {
      gl_lds16(Xa[i] + kk, &As[(tid + i * 256) * 8]);
      gl_lds16(Wb[i] + kk, &Bs[(tid + i * 256) * 8]);
    }
    __syncthreads();
    // R9 fix: 2 k-slices of 32 ushorts (one mfma K=32 each), colu = ks*32+lk*8
#pragma unroll
    for (int ks = 0; ks < 2; ++ks) {
      short8 a[4], b[4];
#pragma unroll
      for (int t = 0; t < 4; ++t) {
        a[t] = *(const short8*)(&As[swz(wm * 64 + t * 16 + lrow, ks * 32 + lk * 8)]);
        b[t] = *(const short8*)(&Bs[swz(wn * 64 + t * 16 + lrow, ks * 32 + lk * 8)]);
      }
#pragma unroll
      for (int mt = 0; mt < 4; ++mt)
#pragma unroll
        for (int nt = 0; nt < 4; ++nt)
          acc[mt][nt] = __builtin_amdgcn_mfma_f32_16x16x32_bf16(a[mt], b[nt], acc[mt][nt], 0, 0, 0);
    }
    __syncthreads();
  }
#pragma unroll
  for (int nt = 0; nt < 4; ++nt) {
    const int col = n0 + wn * 64 + nt * 16 + lrow;
    const float bv = bf2f(bb[z * D_MODEL + col]);
#pragma unroll
    for (int mt = 0; mt < 4; ++mt)
      store_cd(z, Out, m0 + wm * 64 + mt * 16 + lk * 4, col, acc[mt][nt], bv, sc);
  }
}

// ============ kernel 1 (med): raw X (sniffed), pre-built Wt bf16 ============
#define LDA 40
__global__ __launch_bounds__(256) void qkv_gemm_med(
    const unsigned short* __restrict__ X, const unsigned short* __restrict__ Wt,
    const unsigned short* __restrict__ bb,
    unsigned short* __restrict__ Oq, unsigned short* __restrict__ Ok,
    unsigned short* __restrict__ Ov) {
  const int z = blockIdx.z;
  const unsigned short* Wz = Wt + ((size_t)z << 20);
  unsigned short* Out = (z == 0) ? Oq : ((z == 1) ? Ok : Ov);
  const float sc = (z == 0) ? CSC : 1.0f;

  __shared__ alignas(16) unsigned short As[128 * LDA];
  __shared__ alignas(16) unsigned short Bs[128 * LDA];

  const int isbf = sniff_bf16(X);
  const int tid  = threadIdx.x;
  const int wave = tid >> 6, lane = tid & 63;
  const int wm = wave >> 1, wn = wave & 1;
  const int lrow = lane & 15, lk = lane >> 4;
  const int m0 = blockIdx.y * 128;
  const int n0 = blockIdx.x * 128;

  f32x4 acc[4][4] = {};

  for (int kk = 0; kk < D_MODEL; kk += 32) {
#pragma unroll
    for (int i = 0; i < 2; ++i) {
      const int c = tid + i * 256;
      const int row = c >> 2, off = (c & 3) * 8;
      if (isbf) {
        *(uint4*)(&As[row * LDA + off]) =
            *(const uint4*)(X + (size_t)(m0 + row) * D_MODEL + kk + off);
      } else {
        const float* Xf = (const float*)X;
        const float4 f0 = *(const float4*)(Xf + (size_t)(m0 + row) * D_MODEL + kk + off);
        const float4 f1 = *(const float4*)(Xf + (size_t)(m0 + row) * D_MODEL + kk + off + 4);
        unsigned int t[4] = {cvtpk_bf16(f0.x, f0.y), cvtpk_bf16(f0.z, f0.w),
                             cvtpk_bf16(f1.x, f1.y), cvtpk_bf16(f1.z, f1.w)};
        *(uint4*)(&As[row * LDA + off]) = *(const uint4*)t;
      }
      *(uint4*)(&Bs[row * LDA + off]) =
          *(const uint4*)(Wz + (size_t)(n0 + row) * D_MODEL + kk + off);
    }
    __syncthreads();
    short8 a[4], b[4];
#pragma unroll
    for (int t = 0; t < 4; ++t) {
      a[t] = *(const short8*)(&As[(wm * 64 + t * 16 + lrow) * LDA + lk * 8]);
      b[t] = *(const short8*)(&Bs[(wn * 64 + t * 16 + lrow) * LDA + lk * 8]);
    }
#pragma unroll
    for (int mt = 0; mt < 4; ++mt)
#pragma unroll
      for (int nt = 0; nt < 4; ++nt)
        acc[mt][nt] = __builtin_amdgcn_mfma_f32_16x16x32_bf16(a[mt], b[nt], acc[mt][nt], 0, 0, 0);
    __syncthreads();
  }
#pragma unroll
  for (int nt = 0; nt < 4; ++nt) {
    const int col = n0 + wn * 64 + nt * 16 + lrow;
    const float bv = bf2f(bb[z * D_MODEL + col]);
#pragma unroll
    for (int mt = 0; mt < 4; ++mt)
      store_cd(z, Out, m0 + wm * 64 + mt * 16 + lk * 4, col, acc[mt][nt], bv, sc);
  }
}

// ============ kernel 1 (fallback): sniffed dual-dtype, inline transpose =====
__global__ __launch_bounds__(256) void qkv_gemm(
    const unsigned short* __restrict__ X,
    const unsigned short* __restrict__ Wq, const unsigned short* __restrict__ Wk,
    const unsigned short* __restrict__ Wv,
    const unsigned short* __restrict__ bq, const unsigned short* __restrict__ bk,
    const unsigned short* __restrict__ bv,
    unsigned short* __restrict__ Oq, unsigned short* __restrict__ Ok,
    unsigned short* __restrict__ Ov) {
  const int z = blockIdx.z;
  const unsigned short* W    = (z == 0) ? Wq : ((z == 1) ? Wk : Wv);
  const unsigned short* bias = (z == 0) ? bq : ((z == 1) ? bk : bv);
  unsigned short*       Out  = (z == 0) ? Oq : ((z == 1) ? Ok : Ov);
  const float sc = (z == 0) ? CSC : 1.0f;

  __shared__ alignas(16) unsigned short As[128 * LDA];
  __shared__ alignas(16) unsigned short Bs[128 * LDA];

  const int isbf = sniff_bf16(X);
  const int tid  = threadIdx.x;
  const int wave = tid >> 6, lane = tid & 63;
  const int wm = wave >> 1, wn = wave & 1;
  const int lrow = lane & 15, lk = lane >> 4;
  const int m0 = blockIdx.y * 128;
  const int n0 = blockIdx.x * 128;

  f32x4 acc[4][4] = {};

  for (int kk = 0; kk < D_MODEL; kk += 32) {
#pragma unroll
    for (int i = 0; i < 2; ++i) {
      const int c = tid + i * 256;
      const int row = c >> 2, off = (c & 3) * 8;
      if (isbf) {
        *(uint4*)(&As[row * LDA + off]) =
            *(const uint4*)(X + (size_t)(m0 + row) * D_MODEL + kk + off);
      } else {
        const float* Xf = (const float*)X;
        const float4 f0 = *(const float4*)(Xf + (size_t)(m0 + row) * D_MODEL + kk + off);
        const float4 f1 = *(const float4*)(Xf + (size_t)(m0 + row) * D_MODEL + kk + off + 4);
        unsigned int t[4] = {cvtpk_bf16(f0.x, f0.y), cvtpk_bf16(f0.z, f0.w),
                             cvtpk_bf16(f1.x, f1.y), cvtpk_bf16(f1.z, f1.w)};
        *(uint4*)(&As[row * LDA + off]) = *(const uint4*)t;
      }
    }
#pragma unroll
    for (int i = 0; i < 2; ++i) {
      const int c = tid + i * 256;
      const int krow = c & 31;
      const int nc0 = (c >> 5) * 8;
      if (isbf) {
        uint4 v = *(const uint4*)(W + (size_t)(kk + krow) * D_MODEL + n0 + nc0);
        const unsigned short* e = (const unsigned short*)&v;
#pragma unroll
        for (int j = 0; j < 8; ++j) Bs[(nc0 + j) * LDA + krow] = e[j];
      } else {
        const float* Wf = (const float*)W;
        const float4 f0 = *(const float4*)(Wf + (size_t)(kk + krow) * D_MODEL + n0 + nc0);
        const float4 f1 = *(const float4*)(Wf + (size_t)(kk + krow) * D_MODEL + n0 + nc0 + 4);
        const float vals[8] = {f0.x, f0.y, f0.z, f0.w, f1.x, f1.y, f1.z, f1.w};
#pragma unroll
        for (int j = 0; j < 8; ++j) Bs[(nc0 + j) * LDA + krow] = f2bf(vals[j]);
      }
    }
    __syncthreads();
    short8 a[4], b[4];
#pragma unroll
    for (int t = 0; t < 4; ++t) {
      a[t] = *(const short8*)(&As[(wm * 64 + t * 16 + lrow) * LDA + lk * 8]);
      b[t] = *(const short8*)(&Bs[(wn * 64 + t * 16 + lrow) * LDA + lk * 8]);
    }
#pragma unroll
    for (int mt = 0; mt < 4; ++mt)
#pragma unroll
      for (int nt = 0; nt < 4; ++nt)
        acc[mt][nt] = __builtin_amdgcn_mfma_f32_16x16x32_bf16(a[mt], b[nt], acc[mt][nt], 0, 0, 0);
    __syncthreads();
  }
#pragma unroll
  for (int nt = 0; nt < 4; ++nt) {
    const int col = n0 + wn * 64 + nt * 16 + lrow;
    const float bv2 = isbf ? bf2f(bias[col]) : ((const float*)bias)[col];
#pragma unroll
    for (int mt = 0; mt < 4; ++mt)
      store_cd(z, Out, m0 + wm * 64 + mt * 16 + lk * 4, col, acc[mt][nt], bv2, sc);
  }
}

// ================= kernel 2: attention (FROZEN at R4 structure) =============
__global__ __launch_bounds__(256, 4) void attn(
    const unsigned short* __restrict__ Qg, const unsigned short* __restrict__ Kg,
    const unsigned short* __restrict__ Vtg, unsigned short* __restrict__ Outg,
    const unsigned short* __restrict__ Xs) {
  const int lin = blockIdx.y * 32 + blockIdx.x;
  const int xcd = lin & 7, idx = lin >> 3;
  const int bh = xcd * 4 + (idx >> 5);
  const int qt = idx & 31;
  const int b = bh >> 4, h = bh & 15;
  const size_t baseR = (size_t)b * SEQ * D_MODEL + h * HDIM;
  const size_t baseV = (size_t)bh * HDIM * SEQ;

  __shared__ alignas(16) unsigned short Ks[64 * 64];
  __shared__ alignas(16) unsigned short Vs[64 * 64];
  __shared__ alignas(16) unsigned short Ps[64 * 64];

  const int isbf = sniff_bf16(Xs);
  const int tid  = threadIdx.x;
  const int wave = tid >> 6, lane = tid & 63;
  const int lrow = lane & 15, lk = lane >> 4;
  const int q0 = qt * 64;
  const int wq = wave * 16;

  const int c0 = tid,       r0 = c0 >> 3, g0 = ((c0 & 7) ^ (r0 & 7)) * 8;
  const int c1 = tid + 256, r1 = c1 >> 3, g1 = ((c1 & 7) ^ (r1 & 7)) * 8;
  const unsigned short* Kg0 = Kg  + baseR + (size_t)r0 * D_MODEL + g0;
  const unsigned short* Kg1 = Kg  + baseR + (size_t)r1 * D_MODEL + g1;
  const unsigned short* Vg0 = Vtg + baseV + (size_t)r0 * SEQ + g0;
  const unsigned short* Vg1 = Vtg + baseV + (size_t)r1 * SEQ + g1;

  short8 qf[2];
#pragma unroll
  for (int ks = 0; ks < 2; ++ks)
    qf[ks] = *(const short8*)(Qg + baseR +
        (size_t)(q0 + wq + lrow) * D_MODEL + ks * 32 + lk * 8);

  f32x4 accO[4] = {};
  float lsum = 0.f;

#pragma unroll 1
  for (int kv0 = 0; kv0 < SEQ; kv0 += 64) {
    __syncthreads();
    gl_lds16(Kg0 + (size_t)kv0 * D_MODEL, &Ks[c0 * 8]);
    gl_lds16(Kg1 + (size_t)kv0 * D_MODEL, &Ks[c1 * 8]);
    gl_lds16(Vg0 + kv0, &Vs[c0 * 8]);
    gl_lds16(Vg1 + kv0, &Vs[c1 * 8]);
    __syncthreads();

    f32x4 accST[4] = {};
#pragma unroll
    for (int ks = 0; ks < 2; ++ks) {
      short8 kf[4];
#pragma unroll
      for (int mt = 0; mt < 4; ++mt)
        kf[mt] = *(const short8*)(&Ks[swz(mt * 16 + lrow, ks * 32 + lk * 8)]);
#pragma unroll
      for (int mt = 0; mt < 4; ++mt)
        accST[mt] = __builtin_amdgcn_mfma_f32_16x16x32_bf16(
            kf[mt], qf[ks], accST[mt], 0, 0, 0);
    }

#pragma unroll
    for (int mt = 0; mt < 4; ++mt) {
      const float p0 = exp2f(accST[mt][0]), p1 = exp2f(accST[mt][1]);
      const float p2 = exp2f(accST[mt][2]), p3 = exp2f(accST[mt][3]);
      lsum += (p0 + p1) + (p2 + p3);
      uint2 pk;
      pk.x = cvtpk_bf16(p0, p1);
      pk.y = cvtpk_bf16(p2, p3);
      *(uint2*)(&Ps[swz(wq + lrow, mt * 16 + lk * 4)]) = pk;
    }

#pragma unroll
    for (int ks = 0; ks < 2; ++ks) {
      short8 vf[4];
      const short8 pf = *(const short8*)(&Ps[swz(wq + lrow, ks * 32 + lk * 8)]);
#pragma unroll
      for (int nd = 0; nd < 4; ++nd)
        vf[nd] = *(const short8*)(&Vs[swz(nd * 16 + lrow, ks * 32 + lk * 8)]);
#pragma unroll
      for (int nd = 0; nd < 4; ++nd)
        accO[nd] = __builtin_amdgcn_mfma_f32_16x16x32_bf16(
            pf, vf[nd], accO[nd], 0, 0, 0);
    }
  }

  lsum += __shfl_xor(lsum, 16, 64);
  lsum += __shfl_xor(lsum, 32, 64);
  __syncthreads();
  float* Lf = (float*)Ps;
  if (lk == 0) Lf[wq + lrow] = lsum;
  __syncthreads();
  const f32x4 l4 = *(const f32x4*)(&Lf[wq + lk * 4]);
#pragma unroll
  for (int r = 0; r < 4; ++r) {
    const float inv = 1.0f / l4[r];
    const int row = q0 + wq + lk * 4 + r;
#pragma unroll
    for (int nd = 0; nd < 4; ++nd) {
      const int col = h * HDIM + nd * 16 + lrow;
      const float val = accO[nd][r] * inv;
      const size_t idx = (size_t)b * SEQ * D_MODEL + (size_t)row * D_MODEL + col;
      if (isbf) Outg[idx] = f2bf(val);
      else      ((float*)Outg)[idx] = val;
    }
  }
}

extern "C" void kernel_launch(void* const* d_in, const int* in_sizes, int n_in,
                              void* d_out, int out_size, void* d_ws, size_t ws_size,
                              hipStream_t stream) {
  const unsigned short* x  = (const unsigned short*)d_in[0];
  const unsigned short* Wq = (const unsigned short*)d_in[1];
  const unsigned short* bq = (const unsigned short*)d_in[2];
  const unsigned short* Wk = (const unsigned short*)d_in[3];
  const unsigned short* bk = (const unsigned short*)d_in[4];
  const unsigned short* Wv = (const unsigned short*)d_in[5];
  const unsigned short* bv = (const unsigned short*)d_in[6];
  unsigned short* out = (unsigned short*)d_out;
  unsigned short* ws  = (unsigned short*)d_ws;

  const size_t M1 = 1u << 20;            // 1M elements = 2 MB
  const size_t wsE = ws_size / 2;

  unsigned short* Wt  = ws;
  unsigned short* bb  = ws + 3 * M1;
  unsigned short* K   = ws + 3 * M1 + 65536;
  unsigned short* Vt  = K + 4 * M1;
  unsigned short* Xbf = Vt + 4 * M1;
  unsigned short* Q;

  if (wsE >= 19 * M1 + 65536) {          // FULL: everything in ws
    Q = Xbf + 4 * M1;
    cvt_x<<<dim3(2048), 256, 0, stream>>>(x, Xbf);
    cvt_w<<<dim3(32, 32, 3), 256, 0, stream>>>(Wq, Wk, Wv, bq, bk, bv, Wt, bb);
    qkv_gemm_fast<<<dim3(8, 32, 3), 256, 0, stream>>>(Xbf, Wt, bb, Q, K, Vt);
  } else if (wsE >= 15 * M1 + 65536) {   // FAST: Q parked in d_out
    Q = out;
    cvt_x<<<dim3(2048), 256, 0, stream>>>(x, Xbf);
    cvt_w<<<dim3(32, 32, 3), 256, 0, stream>>>(Wq, Wk, Wv, bq, bk, bv, Wt, bb);
    qkv_gemm_fast<<<dim3(8, 32, 3), 256, 0, stream>>>(Xbf, Wt, bb, Q, K, Vt);
  } else if (wsE >= 11 * M1 + 65536) {   // MED: no Xbf, inline X convert
    Q = out;
    cvt_w<<<dim3(32, 32, 3), 256, 0, stream>>>(Wq, Wk, Wv, bq, bk, bv, Wt, bb);
    qkv_gemm_med<<<dim3(8, 32, 3), 256, 0, stream>>>(x, Wt, bb, Q, K, Vt);
  } else {                                // FALLBACK (ws >= 16 MB)
    if (wsE >= 12 * M1) { Q = ws; K = ws + 4 * M1; Vt = ws + 8 * M1; }
    else                { Q = out; K = ws; Vt = ws + 4 * M1; }
    qkv_gemm<<<dim3(8, 32, 3), 256, 0, stream>>>(x, Wq, Wk, Wv, bq, bk, bv, Q, K, Vt);
  }
  attn<<<dim3(32, 32), 256, 0, stream>>>(Q, K, Vt, out, x);
}

// Round 11
// 185.674 us; speedup vs baseline: 1.0775x; 1.0775x over previous
//
#include <hip/hip_runtime.h>

// y = softmax((xWq+bq)(xWk+bk)^T / sqrt(64)) (xWv+bv), per head, NO causal mask.
// B=2, S=2048, D=1024, H=16, hd=64. Input dtype sniffed on-device (fp32 vs bf16).
// R1: csc folded into Q epilogue; v_cvt_pk_bf16_f32 packs. (kept)
// R2: dbuf+prefetch attn — REGRESSED (occupancy 19->11%). Reverted.
// R3: 64-q blocks (grid 1024, 4 blk/CU), XCD swizzle (FETCH 70->12MB). (kept)
// R4: [64][64] LDS + XOR swizzle + gl_lds staging (conflicts 11.5M->2.1M). (kept)
// R5: attn dbuf+prefetch+setprio — REGRESSED. Reverted; attn FROZEN at R4.
// R6-R10: GEMM BK=64+swizzle — NEUTRAL-to-NEGATIVE (total 192->200). At 12
//     waves/CU TLP already hides barrier drain (same lesson as R2/R5).
// R11: GEMM reverted to exact R4 shape (BK=32, 16KB LDS). cvt_x+cvt_w merged
//     into one cvt_xw launch (one fewer dispatch + gap).

#define D_MODEL 1024
#define NHEAD   16
#define HDIM    64
#define SEQ     2048
#define CSC     0.18033688011112042f   // log2(e)/sqrt(64)

typedef __attribute__((ext_vector_type(8))) short short8;
typedef __attribute__((ext_vector_type(4))) float f32x4;

__device__ __forceinline__ float bf2f(unsigned short u) {
  return __uint_as_float(((unsigned int)u) << 16);
}
__device__ __forceinline__ unsigned short f2bf(float f) {
  unsigned int u = __float_as_uint(f);
  u += 0x7fff + ((u >> 16) & 1);   // RNE
  return (unsigned short)(u >> 16);
}
__device__ __forceinline__ unsigned int cvtpk_bf16(float lo, float hi) {
  unsigned int r;
  asm("v_cvt_pk_bf16_f32 %0, %1, %2" : "=v"(r) : "v"(lo), "v"(hi));
  return r;
}

__device__ __forceinline__ int sniff_bf16(const unsigned short* x) {
  int cnt = 0;
#pragma unroll
  for (int i = 0; i < 64; ++i) {
    const unsigned e = (x[2 * i] >> 7) & 0xFF;
    cnt += (e >= 105 && e <= 140) ? 1 : 0;
  }
  return cnt >= 48;
}

__device__ __forceinline__ void gl_lds16(const unsigned short* g, unsigned short* l) {
  __builtin_amdgcn_global_load_lds(
      (const __attribute__((address_space(1))) unsigned int*)g,
      (__attribute__((address_space(3))) unsigned int*)l, 16, 0, 0);
}

// XOR swizzle for [N][64]-ushort LDS tiles (128B rows): 16B chunk ^= row&7.
__device__ __forceinline__ int swz(int row, int colu) {
  return row * 64 + (colu ^ ((row & 7) << 3));
}

// ====== merged pre-kernel: z<3 -> W transpose+bias; z==3 -> X convert =======
__global__ __launch_bounds__(256) void cvt_xw(
    const unsigned short* __restrict__ X,
    const unsigned short* __restrict__ w0, const unsigned short* __restrict__ w1,
    const unsigned short* __restrict__ w2,
    const unsigned short* __restrict__ b0, const unsigned short* __restrict__ b1,
    const unsigned short* __restrict__ b2,
    unsigned short* __restrict__ Xbf,
    unsigned short* __restrict__ Wt, unsigned short* __restrict__ bb) {
  __shared__ unsigned short tile[32][33];
  const int z = blockIdx.z;
  if (z < 3) {
    const unsigned short* W    = (z == 0) ? w0 : ((z == 1) ? w1 : w2);
    const unsigned short* bias = (z == 0) ? b0 : ((z == 1) ? b1 : b2);
    unsigned short* Wtz = Wt + ((size_t)z << 20);
    const int isbf = sniff_bf16(W);
    const int bx = blockIdx.x * 32;      // source col (n)
    const int by = blockIdx.y * 32;      // source row (k)
    const int tx = threadIdx.x & 31;
    const int ty = threadIdx.x >> 5;
#pragma unroll
    for (int r = ty; r < 32; r += 8) {
      unsigned short v;
      if (isbf) v = W[(size_t)(by + r) * D_MODEL + bx + tx];
      else      v = f2bf(((const float*)W)[(size_t)(by + r) * D_MODEL + bx + tx]);
      tile[r][tx] = v;
    }
    __syncthreads();
#pragma unroll
    for (int r = ty; r < 32; r += 8)
      Wtz[(size_t)(bx + r) * D_MODEL + by + tx] = tile[tx][r];
    if (blockIdx.x == 0 && blockIdx.y == 0) {
      const int i0 = threadIdx.x * 4;
#pragma unroll
      for (int j = 0; j < 4; ++j)
        bb[z * D_MODEL + i0 + j] =
            isbf ? bias[i0 + j] : f2bf(((const float*)bias)[i0 + j]);
    }
  } else {
    // X convert: 1024 blocks x 2 slabs x 256 threads x 8 elems = 4.19M elems
    const int isbf = sniff_bf16(X);
    const int lin = blockIdx.y * 32 + blockIdx.x;    // 0..1023
#pragma unroll
    for (int i = 0; i < 2; ++i) {
      const size_t i0 = (((size_t)(lin + i * 1024)) * 256 + threadIdx.x) * 8;
      if (isbf) {
        *(uint4*)(Xbf + i0) = *(const uint4*)(X + i0);
      } else {
        const float* Xf = (const float*)X;
        const float4 f0 = *(const float4*)(Xf + i0);
        const float4 f1 = *(const float4*)(Xf + i0 + 4);
        unsigned int t[4] = {cvtpk_bf16(f0.x, f0.y), cvtpk_bf16(f0.z, f0.w),
                             cvtpk_bf16(f1.x, f1.y), cvtpk_bf16(f1.z, f1.w)};
        *(uint4*)(Xbf + i0) = *(const uint4*)t;
      }
    }
  }
}

// ====== standalone cvt_w (MED path only) ====================================
__global__ __launch_bounds__(256) void cvt_w(
    const unsigned short* __restrict__ w0, const unsigned short* __restrict__ w1,
    const unsigned short* __restrict__ w2,
    const unsigned short* __restrict__ b0, const unsigned short* __restrict__ b1,
    const unsigned short* __restrict__ b2,
    unsigned short* __restrict__ Wt, unsigned short* __restrict__ bb) {
  __shared__ unsigned short tile[32][33];
  const int z = blockIdx.z;
  const unsigned short* W    = (z == 0) ? w0 : ((z == 1) ? w1 : w2);
  const unsigned short* bias = (z == 0) ? b0 : ((z == 1) ? b1 : b2);
  unsigned short* Wtz = Wt + ((size_t)z << 20);
  const int isbf = sniff_bf16(W);
  const int bx = blockIdx.x * 32;
  const int by = blockIdx.y * 32;
  const int tx = threadIdx.x & 31;
  const int ty = threadIdx.x >> 5;
#pragma unroll
  for (int r = ty; r < 32; r += 8) {
    unsigned short v;
    if (isbf) v = W[(size_t)(by + r) * D_MODEL + bx + tx];
    else      v = f2bf(((const float*)W)[(size_t)(by + r) * D_MODEL + bx + tx]);
    tile[r][tx] = v;
  }
  __syncthreads();
#pragma unroll
  for (int r = ty; r < 32; r += 8)
    Wtz[(size_t)(bx + r) * D_MODEL + by + tx] = tile[tx][r];
  if (blockIdx.x == 0 && blockIdx.y == 0) {
    const int i0 = threadIdx.x * 4;
#pragma unroll
    for (int j = 0; j < 4; ++j)
      bb[z * D_MODEL + i0 + j] =
          isbf ? bias[i0 + j] : f2bf(((const float*)bias)[i0 + j]);
  }
}

// ===== shared epilogue helper =====
__device__ __forceinline__ void store_cd(int z, unsigned short* Out, int row0,
                                         int col, const f32x4 acc, float bb,
                                         float sc) {
  if (z == 2) {
    const int b = row0 >> 11, s = row0 & 2047;
    const int bh = b * NHEAD + (col >> 6);
    uint2 pk;
    pk.x = cvtpk_bf16(acc[0] + bb, acc[1] + bb);
    pk.y = cvtpk_bf16(acc[2] + bb, acc[3] + bb);
    *(uint2*)(Out + ((size_t)bh * HDIM + (col & 63)) * SEQ + s) = pk;
  } else {
#pragma unroll
    for (int r = 0; r < 4; ++r)
      Out[(size_t)(row0 + r) * D_MODEL + col] = f2bf((acc[r] + bb) * sc);
  }
}

// ============ kernel 1 (fast): R4-exact m97-style GEMM, BK=32, gl_lds =======
__global__ __launch_bounds__(256) void qkv_gemm_fast(
    const unsigned short* __restrict__ Xbf, const unsigned short* __restrict__ Wt,
    const unsigned short* __restrict__ bb,
    unsigned short* __restrict__ Oq, unsigned short* __restrict__ Ok,
    unsigned short* __restrict__ Ov) {
  const int z = blockIdx.z;
  const unsigned short* Wz = Wt + ((size_t)z << 20);
  unsigned short* Out = (z == 0) ? Oq : ((z == 1) ? Ok : Ov);
  const float sc = (z == 0) ? CSC : 1.0f;

  __shared__ unsigned short As[128 * 32];
  __shared__ unsigned short Bs[128 * 32];

  const int tid  = threadIdx.x;
  const int wave = tid >> 6, lane = tid & 63;
  const int wm = wave >> 1, wn = wave & 1;
  const int lrow = lane & 15, lk = lane >> 4;
  const int m0 = blockIdx.y * 128;
  const int n0 = blockIdx.x * 128;

  f32x4 acc[4][4] = {};

  for (int kk = 0; kk < D_MODEL; kk += 32) {
#pragma unroll
    for (int i = 0; i < 2; ++i) {
      const int c = i * 256 + tid;            // 0..511 chunks of 16 B
      const int row = c >> 2, off = (c & 3) * 8;
      gl_lds16(Xbf + (size_t)(m0 + row) * D_MODEL + kk + off, &As[c * 8]);
      gl_lds16(Wz  + (size_t)(n0 + row) * D_MODEL + kk + off, &Bs[c * 8]);
    }
    __syncthreads();
    short8 a[4], b[4];
#pragma unroll
    for (int t = 0; t < 4; ++t) {
      a[t] = *(const short8*)(&As[(wm * 64 + t * 16 + lrow) * 32 + lk * 8]);
      b[t] = *(const short8*)(&Bs[(wn * 64 + t * 16 + lrow) * 32 + lk * 8]);
    }
#pragma unroll
    for (int mt = 0; mt < 4; ++mt)
#pragma unroll
      for (int nt = 0; nt < 4; ++nt)
        acc[mt][nt] = __builtin_amdgcn_mfma_f32_16x16x32_bf16(a[mt], b[nt], acc[mt][nt], 0, 0, 0);
    __syncthreads();
  }
#pragma unroll
  for (int nt = 0; nt < 4; ++nt) {
    const int col = n0 + wn * 64 + nt * 16 + lrow;
    const float bv = bf2f(bb[z * D_MODEL + col]);
#pragma unroll
    for (int mt = 0; mt < 4; ++mt)
      store_cd(z, Out, m0 + wm * 64 + mt * 16 + lk * 4, col, acc[mt][nt], bv, sc);
  }
}

// ============ kernel 1 (med): raw X (sniffed), pre-built Wt bf16 ============
#define LDA 40
__global__ __launch_bounds__(256) void qkv_gemm_med(
    const unsigned short* __restrict__ X, const unsigned short* __restrict__ Wt,
    const unsigned short* __restrict__ bb,
    unsigned short* __restrict__ Oq, unsigned short* __restrict__ Ok,
    unsigned short* __restrict__ Ov) {
  const int z = blockIdx.z;
  const unsigned short* Wz = Wt + ((size_t)z << 20);
  unsigned short* Out = (z == 0) ? Oq : ((z == 1) ? Ok : Ov);
  const float sc = (z == 0) ? CSC : 1.0f;

  __shared__ alignas(16) unsigned short As[128 * LDA];
  __shared__ alignas(16) unsigned short Bs[128 * LDA];

  const int isbf = sniff_bf16(X);
  const int tid  = threadIdx.x;
  const int wave = tid >> 6, lane = tid & 63;
  const int wm = wave >> 1, wn = wave & 1;
  const int lrow = lane & 15, lk = lane >> 4;
  const int m0 = blockIdx.y * 128;
  const int n0 = blockIdx.x * 128;

  f32x4 acc[4][4] = {};

  for (int kk = 0; kk < D_MODEL; kk += 32) {
#pragma unroll
    for (int i = 0; i < 2; ++i) {
      const int c = tid + i * 256;
      const int row = c >> 2, off = (c & 3) * 8;
      if (isbf) {
        *(uint4*)(&As[row * LDA + off]) =
            *(const uint4*)(X + (size_t)(m0 + row) * D_MODEL + kk + off);
      } else {
        const float* Xf = (const float*)X;
        const float4 f0 = *(const float4*)(Xf + (size_t)(m0 + row) * D_MODEL + kk + off);
        const float4 f1 = *(const float4*)(Xf + (size_t)(m0 + row) * D_MODEL + kk + off + 4);
        unsigned int t[4] = {cvtpk_bf16(f0.x, f0.y), cvtpk_bf16(f0.z, f0.w),
                             cvtpk_bf16(f1.x, f1.y), cvtpk_bf16(f1.z, f1.w)};
        *(uint4*)(&As[row * LDA + off]) = *(const uint4*)t;
      }
      *(uint4*)(&Bs[row * LDA + off]) =
          *(const uint4*)(Wz + (size_t)(n0 + row) * D_MODEL + kk + off);
    }
    __syncthreads();
    short8 a[4], b[4];
#pragma unroll
    for (int t = 0; t < 4; ++t) {
      a[t] = *(const short8*)(&As[(wm * 64 + t * 16 + lrow) * LDA + lk * 8]);
      b[t] = *(const short8*)(&Bs[(wn * 64 + t * 16 + lrow) * LDA + lk * 8]);
    }
#pragma unroll
    for (int mt = 0; mt < 4; ++mt)
#pragma unroll
      for (int nt = 0; nt < 4; ++nt)
        acc[mt][nt] = __builtin_amdgcn_mfma_f32_16x16x32_bf16(a[mt], b[nt], acc[mt][nt], 0, 0, 0);
    __syncthreads();
  }
#pragma unroll
  for (int nt = 0; nt < 4; ++nt) {
    const int col = n0 + wn * 64 + nt * 16 + lrow;
    const float bv = bf2f(bb[z * D_MODEL + col]);
#pragma unroll
    for (int mt = 0; mt < 4; ++mt)
      store_cd(z, Out, m0 + wm * 64 + mt * 16 + lk * 4, col, acc[mt][nt], bv, sc);
  }
}

// ============ kernel 1 (fallback): sniffed dual-dtype, inline transpose =====
__global__ __launch_bounds__(256) void qkv_gemm(
    const unsigned short* __restrict__ X,
    const unsigned short* __restrict__ Wq, const unsigned short* __restrict__ Wk,
    const unsigned short* __restrict__ Wv,
    const unsigned short* __restrict__ bq, const unsigned short* __restrict__ bk,
    const unsigned short* __restrict__ bv,
    unsigned short* __restrict__ Oq, unsigned short* __restrict__ Ok,
    unsigned short* __restrict__ Ov) {
  const int z = blockIdx.z;
  const unsigned short* W    = (z == 0) ? Wq : ((z == 1) ? Wk : Wv);
  const unsigned short* bias = (z == 0) ? bq : ((z == 1) ? bk : bv);
  unsigned short*       Out  = (z == 0) ? Oq : ((z == 1) ? Ok : Ov);
  const float sc = (z == 0) ? CSC : 1.0f;

  __shared__ alignas(16) unsigned short As[128 * LDA];
  __shared__ alignas(16) unsigned short Bs[128 * LDA];

  const int isbf = sniff_bf16(X);
  const int tid  = threadIdx.x;
  const int wave = tid >> 6, lane = tid & 63;
  const int wm = wave >> 1, wn = wave & 1;
  const int lrow = lane & 15, lk = lane >> 4;
  const int m0 = blockIdx.y * 128;
  const int n0 = blockIdx.x * 128;

  f32x4 acc[4][4] = {};

  for (int kk = 0; kk < D_MODEL; kk += 32) {
#pragma unroll
    for (int i = 0; i < 2; ++i) {
      const int c = tid + i * 256;
      const int row = c >> 2, off = (c & 3) * 8;
      if (isbf) {
        *(uint4*)(&As[row * LDA + off]) =
            *(const uint4*)(X + (size_t)(m0 + row) * D_MODEL + kk + off);
      } else {
        const float* Xf = (const float*)X;
        const float4 f0 = *(const float4*)(Xf + (size_t)(m0 + row) * D_MODEL + kk + off);
        const float4 f1 = *(const float4*)(Xf + (size_t)(m0 + row) * D_MODEL + kk + off + 4);
        unsigned int t[4] = {cvtpk_bf16(f0.x, f0.y), cvtpk_bf16(f0.z, f0.w),
                             cvtpk_bf16(f1.x, f1.y), cvtpk_bf16(f1.z, f1.w)};
        *(uint4*)(&As[row * LDA + off]) = *(const uint4*)t;
      }
    }
#pragma unroll
    for (int i = 0; i < 2; ++i) {
      const int c = tid + i * 256;
      const int krow = c & 31;
      const int nc0 = (c >> 5) * 8;
      if (isbf) {
        uint4 v = *(const uint4*)(W + (size_t)(kk + krow) * D_MODEL + n0 + nc0);
        const unsigned short* e = (const unsigned short*)&v;
#pragma unroll
        for (int j = 0; j < 8; ++j) Bs[(nc0 + j) * LDA + krow] = e[j];
      } else {
        const float* Wf = (const float*)W;
        const float4 f0 = *(const float4*)(Wf + (size_t)(kk + krow) * D_MODEL + n0 + nc0);
        const float4 f1 = *(const float4*)(Wf + (size_t)(kk + krow) * D_MODEL + n0 + nc0 + 4);
        const float vals[8] = {f0.x, f0.y, f0.z, f0.w, f1.x, f1.y, f1.z, f1.w};
#pragma unroll
        for (int j = 0; j < 8; ++j) Bs[(nc0 + j) * LDA + krow] = f2bf(vals[j]);
      }
    }
    __syncthreads();
    short8 a[4], b[4];
#pragma unroll
    for (int t = 0; t < 4; ++t) {
      a[t] = *(const short8*)(&As[(wm * 64 + t * 16 + lrow) * LDA + lk * 8]);
      b[t] = *(const short8*)(&Bs[(wn * 64 + t * 16 + lrow) * LDA + lk * 8]);
    }
#pragma unroll
    for (int mt = 0; mt < 4; ++mt)
#pragma unroll
      for (int nt = 0; nt < 4; ++nt)
        acc[mt][nt] = __builtin_amdgcn_mfma_f32_16x16x32_bf16(a[mt], b[nt], acc[mt][nt], 0, 0, 0);
    __syncthreads();
  }
#pragma unroll
  for (int nt = 0; nt < 4; ++nt) {
    const int col = n0 + wn * 64 + nt * 16 + lrow;
    const float bv2 = isbf ? bf2f(bias[col]) : ((const float*)bias)[col];
#pragma unroll
    for (int mt = 0; mt < 4; ++mt)
      store_cd(z, Out, m0 + wm * 64 + mt * 16 + lk * 4, col, acc[mt][nt], bv2, sc);
  }
}

// ================= kernel 2: attention (FROZEN at R4 structure) =============
__global__ __launch_bounds__(256, 4) void attn(
    const unsigned short* __restrict__ Qg, const unsigned short* __restrict__ Kg,
    const unsigned short* __restrict__ Vtg, unsigned short* __restrict__ Outg,
    const unsigned short* __restrict__ Xs) {
  const int lin = blockIdx.y * 32 + blockIdx.x;
  const int xcd = lin & 7, idx = lin >> 3;
  const int bh = xcd * 4 + (idx >> 5);
  const int qt = idx & 31;
  const int b = bh >> 4, h = bh & 15;
  const size_t baseR = (size_t)b * SEQ * D_MODEL + h * HDIM;
  const size_t baseV = (size_t)bh * HDIM * SEQ;

  __shared__ alignas(16) unsigned short Ks[64 * 64];
  __shared__ alignas(16) unsigned short Vs[64 * 64];
  __shared__ alignas(16) unsigned short Ps[64 * 64];

  const int isbf = sniff_bf16(Xs);
  const int tid  = threadIdx.x;
  const int wave = tid >> 6, lane = tid & 63;
  const int lrow = lane & 15, lk = lane >> 4;
  const int q0 = qt * 64;
  const int wq = wave * 16;

  const int c0 = tid,       r0 = c0 >> 3, g0 = ((c0 & 7) ^ (r0 & 7)) * 8;
  const int c1 = tid + 256, r1 = c1 >> 3, g1 = ((c1 & 7) ^ (r1 & 7)) * 8;
  const unsigned short* Kg0 = Kg  + baseR + (size_t)r0 * D_MODEL + g0;
  const unsigned short* Kg1 = Kg  + baseR + (size_t)r1 * D_MODEL + g1;
  const unsigned short* Vg0 = Vtg + baseV + (size_t)r0 * SEQ + g0;
  const unsigned short* Vg1 = Vtg + baseV + (size_t)r1 * SEQ + g1;

  short8 qf[2];
#pragma unroll
  for (int ks = 0; ks < 2; ++ks)
    qf[ks] = *(const short8*)(Qg + baseR +
        (size_t)(q0 + wq + lrow) * D_MODEL + ks * 32 + lk * 8);

  f32x4 accO[4] = {};
  float lsum = 0.f;

#pragma unroll 1
  for (int kv0 = 0; kv0 < SEQ; kv0 += 64) {
    __syncthreads();
    gl_lds16(Kg0 + (size_t)kv0 * D_MODEL, &Ks[c0 * 8]);
    gl_lds16(Kg1 + (size_t)kv0 * D_MODEL, &Ks[c1 * 8]);
    gl_lds16(Vg0 + kv0, &Vs[c0 * 8]);
    gl_lds16(Vg1 + kv0, &Vs[c1 * 8]);
    __syncthreads();

    f32x4 accST[4] = {};
#pragma unroll
    for (int ks = 0; ks < 2; ++ks) {
      short8 kf[4];
#pragma unroll
      for (int mt = 0; mt < 4; ++mt)
        kf[mt] = *(const short8*)(&Ks[swz(mt * 16 + lrow, ks * 32 + lk * 8)]);
#pragma unroll
      for (int mt = 0; mt < 4; ++mt)
        accST[mt] = __builtin_amdgcn_mfma_f32_16x16x32_bf16(
            kf[mt], qf[ks], accST[mt], 0, 0, 0);
    }

#pragma unroll
    for (int mt = 0; mt < 4; ++mt) {
      const float p0 = exp2f(accST[mt][0]), p1 = exp2f(accST[mt][1]);
      const float p2 = exp2f(accST[mt][2]), p3 = exp2f(accST[mt][3]);
      lsum += (p0 + p1) + (p2 + p3);
      uint2 pk;
      pk.x = cvtpk_bf16(p0, p1);
      pk.y = cvtpk_bf16(p2, p3);
      *(uint2*)(&Ps[swz(wq + lrow, mt * 16 + lk * 4)]) = pk;
    }

#pragma unroll
    for (int ks = 0; ks < 2; ++ks) {
      short8 vf[4];
      const short8 pf = *(const short8*)(&Ps[swz(wq + lrow, ks * 32 + lk * 8)]);
#pragma unroll
      for (int nd = 0; nd < 4; ++nd)
        vf[nd] = *(const short8*)(&Vs[swz(nd * 16 + lrow, ks * 32 + lk * 8)]);
#pragma unroll
      for (int nd = 0; nd < 4; ++nd)
        accO[nd] = __builtin_amdgcn_mfma_f32_16x16x32_bf16(
            pf, vf[nd], accO[nd], 0, 0, 0);
    }
  }

  lsum += __shfl_xor(lsum, 16, 64);
  lsum += __shfl_xor(lsum, 32, 64);
  __syncthreads();
  float* Lf = (float*)Ps;
  if (lk == 0) Lf[wq + lrow] = lsum;
  __syncthreads();
  const f32x4 l4 = *(const f32x4*)(&Lf[wq + lk * 4]);
#pragma unroll
  for (int r = 0; r < 4; ++r) {
    const float inv = 1.0f / l4[r];
    const int row = q0 + wq + lk * 4 + r;
#pragma unroll
    for (int nd = 0; nd < 4; ++nd) {
      const int col = h * HDIM + nd * 16 + lrow;
      const float val = accO[nd][r] * inv;
      const size_t idx = (size_t)b * SEQ * D_MODEL + (size_t)row * D_MODEL + col;
      if (isbf) Outg[idx] = f2bf(val);
      else      ((float*)Outg)[idx] = val;
    }
  }
}

extern "C" void kernel_launch(void* const* d_in, const int* in_sizes, int n_in,
                              void* d_out, int out_size, void* d_ws, size_t ws_size,
                              hipStream_t stream) {
  const unsigned short* x  = (const unsigned short*)d_in[0];
  const unsigned short* Wq = (const unsigned short*)d_in[1];
  const unsigned short* bq = (const unsigned short*)d_in[2];
  const unsigned short* Wk = (const unsigned short*)d_in[3];
  const unsigned short* bk = (const unsigned short*)d_in[4];
  const unsigned short* Wv = (const unsigned short*)d_in[5];
  const unsigned short* bv = (const unsigned short*)d_in[6];
  unsigned short* out = (unsigned short*)d_out;
  unsigned short* ws  = (unsigned short*)d_ws;

  const size_t M1 = 1u << 20;            // 1M elements = 2 MB
  const size_t wsE = ws_size / 2;

  unsigned short* Wt  = ws;
  unsigned short* bb  = ws + 3 * M1;
  unsigned short* K   = ws + 3 * M1 + 65536;
  unsigned short* Vt  = K + 4 * M1;
  unsigned short* Xbf = Vt + 4 * M1;
  unsigned short* Q;

  if (wsE >= 19 * M1 + 65536) {          // FULL: everything in ws
    Q = Xbf + 4 * M1;
    cvt_xw<<<dim3(32, 32, 4), 256, 0, stream>>>(x, Wq, Wk, Wv, bq, bk, bv,
                                                Xbf, Wt, bb);
    qkv_gemm_fast<<<dim3(8, 32, 3), 256, 0, stream>>>(Xbf, Wt, bb, Q, K, Vt);
  } else if (wsE >= 15 * M1 + 65536) {   // FAST: Q parked in d_out
    Q = out;
    cvt_xw<<<dim3(32, 32, 4), 256, 0, stream>>>(x, Wq, Wk, Wv, bq, bk, bv,
                                                Xbf, Wt, bb);
    qkv_gemm_fast<<<dim3(8, 32, 3), 256, 0, stream>>>(Xbf, Wt, bb, Q, K, Vt);
  } else if (wsE >= 11 * M1 + 65536) {   // MED: no Xbf, inline X convert
    Q = out;
    cvt_w<<<dim3(32, 32, 3), 256, 0, stream>>>(Wq, Wk, Wv, bq, bk, bv, Wt, bb);
    qkv_gemm_med<<<dim3(8, 32, 3), 256, 0, stream>>>(x, Wt, bb, Q, K, Vt);
  } else {                                // FALLBACK (ws >= 16 MB)
    if (wsE >= 12 * M1) { Q = ws; K = ws + 4 * M1; Vt = ws + 8 * M1; }
    else                { Q = out; K = ws; Vt = ws + 4 * M1; }
    qkv_gemm<<<dim3(8, 32, 3), 256, 0, stream>>>(x, Wq, Wk, Wv, bq, bk, bv, Q, K, Vt);
  }
  attn<<<dim3(32, 32), 256, 0, stream>>>(Q, K, Vt, out, x);
}